// Round 1
// baseline (1084.285 us; speedup 1.0000x reference)
//
#include <hip/hip_runtime.h>

#define BLOCK 256   // outer rows per block (one per thread)
#define IC    256   // inner chunk size staged in LDS

__device__ __forceinline__ float wave_reduce_add(float v) {
    #pragma unroll
    for (int off = 32; off > 0; off >>= 1) v += __shfl_down(v, off, 64);
    return v;
}

__global__ __launch_bounds__(BLOCK)
void emd_init(float* __restrict__ satl, float* __restrict__ satr,
              float* __restrict__ out, float fl, float fr,
              int b, int n, int m) {
    int idx = blockIdx.x * blockDim.x + threadIdx.x;
    if (idx < b * n) satl[idx] = fl;
    if (idx < b * m) satr[idx] = fr;
    if (idx < b)     out[idx]  = 0.f;
}

// Pass 1: P1p[b][i][chunk] = sum_{j in chunk} exp(L*d2(i,j)) * satr[j]
// Piggyback (chunk==0, !first): satl update + cost contribution from prev level.
__global__ __launch_bounds__(BLOCK)
void emd_pass1(const float* __restrict__ xyz1, const float* __restrict__ xyz2,
               const float* __restrict__ satr_cur,
               float* __restrict__ P1p,
               float* __restrict__ satl, const float* __restrict__ a_prev,
               const float* __restrict__ P3a, const float* __restrict__ P3b,
               float* __restrict__ cost_out,
               float lscale, int n, int m, int C1, int first)
{
    __shared__ float4 sh[IC];
    const int bb    = blockIdx.z;
    const int i     = blockIdx.x * BLOCK + threadIdx.x;
    const int chunk = blockIdx.y;

    const float* x2 = xyz2 + (size_t)bb * m * 3;
    const float* sr = satr_cur + (size_t)bb * m;
    for (int t = threadIdx.x; t < IC; t += BLOCK) {
        int j = chunk * IC + t;
        sh[t] = make_float4(x2[3*j], x2[3*j+1], x2[3*j+2], sr[j]);
    }

    if (!first && chunk == 0) {
        const size_t ri = (size_t)bb * n + i;
        const float* pa = P3a + ri * (size_t)C1;
        const float* pb = P3b + ri * (size_t)C1;
        float s1 = 0.f, s2 = 0.f;
        for (int c = 0; c < C1; ++c) { s1 += pa[c]; s2 += pb[c]; }
        float av = a_prev[ri];
        satl[ri] = fmaxf(satl[ri] - av * s1, 0.f);
        float cc = wave_reduce_add(av * s2);
        if ((threadIdx.x & 63) == 0) atomicAdd(&cost_out[bb], cc);
    }
    __syncthreads();

    const float* p1 = xyz1 + ((size_t)bb * n + i) * 3;
    const float x = p1[0], y = p1[1], z = p1[2];
    float acc = 0.f;
#pragma unroll 8
    for (int t = 0; t < IC; ++t) {
        float4 q = sh[t];
        float dx = x - q.x, dy = y - q.y, dz = z - q.z;
        float d2 = fmaf(dx, dx, fmaf(dy, dy, dz * dz));
        float e  = __builtin_amdgcn_exp2f(d2 * lscale);
        acc = fmaf(e, q.w, acc);
    }
    P1p[((size_t)bb * n + i) * C1 + chunk] = acc;
}

// Pass 2: P2p[b][j][chunk] = sum_{i in chunk} exp(L*d2(i,j)) * a[i]
// a[i] = satl[i] / (rowsum1[i] + 1e-9) computed at staging; tile-0 blocks persist a[].
__global__ __launch_bounds__(BLOCK)
void emd_pass2(const float* __restrict__ xyz2, const float* __restrict__ xyz1,
               const float* __restrict__ satl, const float* __restrict__ P1p,
               float* __restrict__ a_out, float* __restrict__ P2p,
               float lscale, int n, int m, int C1, int C2)
{
    __shared__ float4 sh[IC];
    const int bb    = blockIdx.z;
    const int j     = blockIdx.x * BLOCK + threadIdx.x;   // outer: xyz2 row
    const int chunk = blockIdx.y;                         // inner chunk over i

    const float* x1 = xyz1 + (size_t)bb * n * 3;
    for (int t = threadIdx.x; t < IC; t += BLOCK) {
        int i = chunk * IC + t;
        size_t ri = (size_t)bb * n + i;
        const float* pp = P1p + ri * (size_t)C1;
        float rs = 0.f;
        for (int c = 0; c < C1; ++c) rs += pp[c];
        float av = satl[ri] / (rs + 1e-9f);
        if (blockIdx.x == 0) a_out[ri] = av;
        sh[t] = make_float4(x1[3*i], x1[3*i+1], x1[3*i+2], av);
    }
    __syncthreads();

    const float* p2 = xyz2 + ((size_t)bb * m + j) * 3;
    const float x = p2[0], y = p2[1], z = p2[2];
    float acc = 0.f;
#pragma unroll 8
    for (int t = 0; t < IC; ++t) {
        float4 q = sh[t];
        float dx = x - q.x, dy = y - q.y, dz = z - q.z;
        float d2 = fmaf(dx, dx, fmaf(dy, dy, dz * dz));
        float e  = __builtin_amdgcn_exp2f(d2 * lscale);
        acc = fmaf(e, q.w, acc);
    }
    P2p[((size_t)bb * m + j) * C2 + chunk] = acc;
}

// Pass 3: s1/s2 partials per row; r2[j] computed at staging from satr + colsumE
// partials; tile-0 blocks write satr_next (ping-pong buffer).
__global__ __launch_bounds__(BLOCK)
void emd_pass3(const float* __restrict__ xyz1, const float* __restrict__ xyz2,
               const float* __restrict__ satr_cur, float* __restrict__ satr_nxt,
               const float* __restrict__ P2p,
               float* __restrict__ P3a, float* __restrict__ P3b,
               float lscale, int n, int m, int C2, int C1)
{
    __shared__ float4 sh[IC];
    const int bb    = blockIdx.z;
    const int i     = blockIdx.x * BLOCK + threadIdx.x;
    const int chunk = blockIdx.y;   // inner chunk over j

    const float* x2 = xyz2 + (size_t)bb * m * 3;
    for (int t = threadIdx.x; t < IC; t += BLOCK) {
        int j = chunk * IC + t;
        size_t rj = (size_t)bb * m + j;
        const float* pp = P2p + rj * (size_t)C2;
        float cs = 0.f;
        for (int c = 0; c < C2; ++c) cs += pp[c];
        float srj = satr_cur[rj];
        float cs2 = srj * cs;            // colsum2 = satr * colsumE
        float ss  = cs2 + 1e-9f;
        float inv = srj / ss;
        float r2  = srj * inv;           // satr^2 / ss
        if (blockIdx.x == 0) satr_nxt[rj] = fmaxf(srj - cs2 * inv, 0.f);
        sh[t] = make_float4(x2[3*j], x2[3*j+1], x2[3*j+2], r2);
    }
    __syncthreads();

    const float* p1 = xyz1 + ((size_t)bb * n + i) * 3;
    const float x = p1[0], y = p1[1], z = p1[2];
    float s1 = 0.f, s2 = 0.f;
#pragma unroll 4
    for (int t = 0; t < IC; ++t) {
        float4 q = sh[t];
        float dx = x - q.x, dy = y - q.y, dz = z - q.z;
        float d2 = fmaf(dx, dx, fmaf(dy, dy, dz * dz));
        float e  = __builtin_amdgcn_exp2f(d2 * lscale);
        float er = e * q.w;
        s1 += er;
        s2 = fmaf(er, __builtin_amdgcn_sqrtf(fmaxf(d2, 1e-12f)), s2);
    }
    size_t ri = (size_t)bb * n + i;
    P3a[ri * (size_t)C1 + chunk] = s1;
    P3b[ri * (size_t)C1 + chunk] = s2;
}

// Final level's cost contribution.
__global__ __launch_bounds__(BLOCK)
void emd_final(const float* __restrict__ a, const float* __restrict__ P3b,
               float* __restrict__ cost_out, int n, int C1)
{
    const int bb = blockIdx.z;
    const int i  = blockIdx.x * BLOCK + threadIdx.x;
    size_t ri = (size_t)bb * n + i;
    const float* pb = P3b + ri * (size_t)C1;
    float s2 = 0.f;
    for (int c = 0; c < C1; ++c) s2 += pb[c];
    float cc = wave_reduce_add(a[ri] * s2);
    if ((threadIdx.x & 63) == 0) atomicAdd(&cost_out[bb], cc);
}

extern "C" void kernel_launch(void* const* d_in, const int* in_sizes, int n_in,
                              void* d_out, int out_size, void* d_ws, size_t ws_size,
                              hipStream_t stream)
{
    const float* xyz1 = (const float*)d_in[0];
    const float* xyz2 = (const float*)d_in[1];
    const int b = out_size;                 // 4
    const int n = in_sizes[0] / (3 * b);    // 4096
    const int m = in_sizes[1] / (3 * b);    // 4096
    const int C1 = m / IC;                  // chunks over j (pass1/pass3 partials)
    const int C2 = n / IC;                  // chunks over i (pass2 partials)

    float* ws    = (float*)d_ws;
    float* satl  = ws; ws += (size_t)b * n;
    float* satr0 = ws; ws += (size_t)b * m;
    float* satr1 = ws; ws += (size_t)b * m;
    float* aArr  = ws; ws += (size_t)b * n;
    float* P1p   = ws; ws += (size_t)b * n * C1;
    float* P2p   = ws; ws += (size_t)b * m * C2;
    float* P3a   = ws; ws += (size_t)b * n * C1;
    float* P3b   = ws; ws += (size_t)b * n * C1;

    float* out = (float*)d_out;

    const int mx = n > m ? n : m;
    const float fl = (float)(mx / n), fr = (float)(mx / m);

    const int initN = b * mx;
    emd_init<<<dim3((initN + BLOCK - 1) / BLOCK), BLOCK, 0, stream>>>(
        satl, satr0, out, fl, fr, b, n, m);

    const double LOG2E = 1.4426950408889634074;
    const double levels[11] = {-65536.0, -16384.0, -4096.0, -1024.0, -256.0,
                               -64.0, -16.0, -4.0, -1.0, -0.25, 0.0};

    for (int L = 0; L < 11; ++L) {
        const float lscale = (float)(levels[L] * LOG2E);
        float* sc = (L & 1) ? satr1 : satr0;
        float* sn = (L & 1) ? satr0 : satr1;
        emd_pass1<<<dim3(n / BLOCK, C1, b), BLOCK, 0, stream>>>(
            xyz1, xyz2, sc, P1p, satl, aArr, P3a, P3b, out,
            lscale, n, m, C1, (L == 0) ? 1 : 0);
        emd_pass2<<<dim3(m / BLOCK, C2, b), BLOCK, 0, stream>>>(
            xyz2, xyz1, satl, P1p, aArr, P2p, lscale, n, m, C1, C2);
        emd_pass3<<<dim3(n / BLOCK, C1, b), BLOCK, 0, stream>>>(
            xyz1, xyz2, sc, sn, P2p, P3a, P3b, lscale, n, m, C2, C1);
    }
    emd_final<<<dim3(n / BLOCK, 1, b), BLOCK, 0, stream>>>(aArr, P3b, out, n, C1);
}

// Round 2
// 959.322 us; speedup vs baseline: 1.1303x; 1.1303x over previous
//
#include <hip/hip_runtime.h>

#define BLOCK 256
#define IC    128          // staged points per chunk
#define RPT   4            // rows per thread
#define ROWS  (BLOCK*RPT)  // 1024 rows per block

__device__ __forceinline__ float wave_reduce_add(float v) {
#pragma unroll
    for (int off = 32; off > 0; off >>= 1) v += __shfl_down(v, off, 64);
    return v;
}
__device__ __forceinline__ float lg2(float x) { return __builtin_amdgcn_logf(x); }
__device__ __forceinline__ float ex2(float x) { return __builtin_amdgcn_exp2f(x); }

__device__ __forceinline__ void load_rows(const float* p, float* x, float* y, float* z) {
    float4 v0 = *(const float4*)p;
    float4 v1 = *(const float4*)(p + 4);
    float4 v2 = *(const float4*)(p + 8);
    x[0]=v0.x; x[1]=v0.w; x[2]=v1.z; x[3]=v2.y;
    y[0]=v0.y; y[1]=v1.x; y[2]=v1.w; y[3]=v2.z;
    z[0]=v0.z; z[1]=v1.y; z[2]=v2.x; z[3]=v2.w;
}

__global__ __launch_bounds__(BLOCK)
void emd_init(float* __restrict__ satl, float* __restrict__ satr,
              float* __restrict__ out, float fl, float fr,
              int b, int n, int m) {
    int idx = blockIdx.x * blockDim.x + threadIdx.x;
    if (idx < b * n) satl[idx] = fl;
    if (idx < b * m) satr[idx] = fr;
    if (idx < b)     out[idx]  = 0.f;
}

// Generic "dot-trick" row pass: acc_i = sum_j exp2(ls*d2(i,j) + log2 w_j)
// pass1: outer = xyz1 rows, staged = xyz2/satr. Only used for level 0.
__global__ __launch_bounds__(BLOCK)
void emd_pass1(const float* __restrict__ xyz1, const float* __restrict__ xyz2,
               const float* __restrict__ satr, float* __restrict__ P1p,
               float ls, int n, int m, int C)
{
    __shared__ float4 sh[IC];
    const int bb = blockIdx.z, chunk = blockIdx.y;
    const float* x2 = xyz2 + (size_t)bb * m * 3;
    const float nls2 = -2.f * ls;
    for (int t = threadIdx.x; t < IC; t += BLOCK) {
        int j = chunk * IC + t;
        float qx = x2[3*j], qy = x2[3*j+1], qz = x2[3*j+2];
        float w  = satr[(size_t)bb * m + j];
        float sc = ls * (qx*qx + qy*qy + qz*qz) + lg2(w);
        sh[t] = make_float4(nls2*qx, nls2*qy, nls2*qz, sc);
    }
    __syncthreads();

    const int i0 = blockIdx.x * ROWS + threadIdx.x * RPT;
    float x[RPT], y[RPT], z[RPT], cc[RPT], acc[RPT];
    load_rows(xyz1 + ((size_t)bb * n + i0) * 3, x, y, z);
#pragma unroll
    for (int r = 0; r < RPT; ++r) {
        cc[r] = ls * (x[r]*x[r] + y[r]*y[r] + z[r]*z[r]);
        acc[r] = 0.f;
    }
#pragma unroll 4
    for (int t = 0; t < IC; ++t) {
        float4 q = sh[t];
#pragma unroll
        for (int r = 0; r < RPT; ++r) {
            float arg = fmaf(x[r], q.x, fmaf(y[r], q.y, fmaf(z[r], q.z, q.w + cc[r])));
            acc[r] += ex2(arg);
        }
    }
#pragma unroll
    for (int r = 0; r < RPT; ++r)
        P1p[((size_t)bb * n + i0 + r) * C + chunk] = acc[r];
}

// pass2: outer = xyz2 rows; staged = xyz1 side with a_i computed in staging.
// Piggyback (levels>=1): satl update (ping-pong) + cost of previous level.
__global__ __launch_bounds__(BLOCK)
void emd_pass2(const float* __restrict__ xyz2, const float* __restrict__ xyz1,
               const float* __restrict__ satlPrev, float* __restrict__ satlNext,
               const float* __restrict__ aPrev, float* __restrict__ aOut,
               const float* __restrict__ P1p, const float* __restrict__ P3a,
               const float* __restrict__ P3b, float* __restrict__ P2p,
               float* __restrict__ cost,
               float ls, int n, int m, int Cr, int Cw, int first)
{
    __shared__ float4 sh[IC];
    const int bb = blockIdx.z, chunk = blockIdx.y;
    const float* x1 = xyz1 + (size_t)bb * n * 3;
    const float nls2 = -2.f * ls;
    for (int t = threadIdx.x; t < IC; t += BLOCK) {
        size_t ri = (size_t)bb * n + chunk * IC + t;
        const float* pp = P1p + ri * Cr;
        float rs = 0.f;
        for (int c = 0; c < Cr; ++c) rs += pp[c];
        float sl, costv = 0.f;
        if (first) {
            sl = satlPrev[ri];
        } else {
            const float* pa = P3a + ri * Cr;
            const float* pb = P3b + ri * Cr;
            float s1 = 0.f, s2 = 0.f;
            for (int c = 0; c < Cr; ++c) { s1 += pa[c]; s2 += pb[c]; }
            float ap = aPrev[ri];
            sl = fmaxf(satlPrev[ri] - ap * s1, 0.f);
            costv = ap * s2;
            if (blockIdx.x == 0) satlNext[ri] = sl;
        }
        float a = sl / (rs + 1e-9f);
        if (blockIdx.x == 0) aOut[ri] = a;
        int jj = 3 * (chunk * IC + t);
        float qx = x1[jj], qy = x1[jj+1], qz = x1[jj+2];
        float sc = ls * (qx*qx + qy*qy + qz*qz) + lg2(a);
        sh[t] = make_float4(nls2*qx, nls2*qy, nls2*qz, sc);
        if (!first && blockIdx.x == 0) {
            float cv = wave_reduce_add(costv);
            if ((threadIdx.x & 63) == 0) atomicAdd(&cost[bb], cv);
        }
    }
    __syncthreads();

    const int j0 = blockIdx.x * ROWS + threadIdx.x * RPT;
    float x[RPT], y[RPT], z[RPT], cc[RPT], acc[RPT];
    load_rows(xyz2 + ((size_t)bb * m + j0) * 3, x, y, z);
#pragma unroll
    for (int r = 0; r < RPT; ++r) {
        cc[r] = ls * (x[r]*x[r] + y[r]*y[r] + z[r]*z[r]);
        acc[r] = 0.f;
    }
#pragma unroll 4
    for (int t = 0; t < IC; ++t) {
        float4 q = sh[t];
#pragma unroll
        for (int r = 0; r < RPT; ++r) {
            float arg = fmaf(x[r], q.x, fmaf(y[r], q.y, fmaf(z[r], q.z, q.w + cc[r])));
            acc[r] += ex2(arg);
        }
    }
#pragma unroll
    for (int r = 0; r < RPT; ++r)
        P2p[((size_t)bb * m + j0 + r) * Cw + chunk] = acc[r];
}

// fused pass3(L) + pass1(L+1): one sweep, d2 computed once.
// staging computes r2, satr_next (analytic) from P2p partials.
__global__ __launch_bounds__(BLOCK)
void emd_fused(const float* __restrict__ xyz1, const float* __restrict__ xyz2,
               const float* __restrict__ satrCur, float* __restrict__ satrNext,
               const float* __restrict__ P2p,
               float* __restrict__ P3a, float* __restrict__ P3b,
               float* __restrict__ P1p,
               float lsA, float lsB, int n, int m, int C2, int C)
{
    __shared__ float4 sh[IC];   // (qx,qy,qz, log2 r2)
    __shared__ float  shB[IC];  // log2 satr_next
    const int bb = blockIdx.z, chunk = blockIdx.y;
    const float* x2 = xyz2 + (size_t)bb * m * 3;
    for (int t = threadIdx.x; t < IC; t += BLOCK) {
        size_t rj = (size_t)bb * m + chunk * IC + t;
        const float* pp = P2p + rj * C2;
        float cs = 0.f;
        for (int c = 0; c < C2; ++c) cs += pp[c];
        float sr  = satrCur[rj];
        float cs2 = sr * cs;
        float inv = sr / (cs2 + 1e-9f);
        float r2  = sr * inv;
        float sn  = fmaxf(sr - cs2 * inv, 0.f);
        if (blockIdx.x == 0) satrNext[rj] = sn;
        int jj = 3 * (chunk * IC + t);
        sh[t]  = make_float4(x2[jj], x2[jj+1], x2[jj+2], lg2(r2));
        shB[t] = lg2(sn);
    }
    __syncthreads();

    const int i0 = blockIdx.x * ROWS + threadIdx.x * RPT;
    float x[RPT], y[RPT], z[RPT];
    load_rows(xyz1 + ((size_t)bb * n + i0) * 3, x, y, z);
    float s1[RPT], s2[RPT], r1[RPT];
#pragma unroll
    for (int r = 0; r < RPT; ++r) { s1[r] = 0.f; s2[r] = 0.f; r1[r] = 0.f; }
#pragma unroll 2
    for (int t = 0; t < IC; ++t) {
        float4 q = sh[t];
        float lb = shB[t];
#pragma unroll
        for (int r = 0; r < RPT; ++r) {
            float dx = x[r] - q.x, dy = y[r] - q.y, dz = z[r] - q.z;
            float d2 = fmaf(dz, dz, fmaf(dy, dy, dx * dx));
            float e3 = ex2(fmaf(d2, lsA, q.w));     // e * r2
            s1[r] += e3;
            float sq = __builtin_amdgcn_sqrtf(fmaxf(d2, 1e-12f));
            s2[r] = fmaf(e3, sq, s2[r]);
            r1[r] += ex2(fmaf(d2, lsB, lb));        // next-level rowsum1 part
        }
    }
#pragma unroll
    for (int r = 0; r < RPT; ++r) {
        size_t ri = (size_t)bb * n + i0 + r;
        P3a[ri * C + chunk] = s1[r];
        P3b[ri * C + chunk] = s2[r];
        P1p[ri * C + chunk] = r1[r];
    }
}

// Last level (level value = 0): exp term == 1, so s2_i = sum_j r2_j * sqrt(d2).
__global__ __launch_bounds__(BLOCK)
void emd_pass3_last(const float* __restrict__ xyz1, const float* __restrict__ xyz2,
                    const float* __restrict__ satrCur, const float* __restrict__ P2p,
                    float* __restrict__ P3b, int n, int m, int C2, int C)
{
    __shared__ float4 sh[IC];   // (qx,qy,qz, r2)
    const int bb = blockIdx.z, chunk = blockIdx.y;
    const float* x2 = xyz2 + (size_t)bb * m * 3;
    for (int t = threadIdx.x; t < IC; t += BLOCK) {
        size_t rj = (size_t)bb * m + chunk * IC + t;
        const float* pp = P2p + rj * C2;
        float cs = 0.f;
        for (int c = 0; c < C2; ++c) cs += pp[c];
        float sr  = satrCur[rj];
        float cs2 = sr * cs;
        float inv = sr / (cs2 + 1e-9f);
        float r2  = sr * inv;
        int jj = 3 * (chunk * IC + t);
        sh[t] = make_float4(x2[jj], x2[jj+1], x2[jj+2], r2);
    }
    __syncthreads();

    const int i0 = blockIdx.x * ROWS + threadIdx.x * RPT;
    float x[RPT], y[RPT], z[RPT], s2[RPT];
    load_rows(xyz1 + ((size_t)bb * n + i0) * 3, x, y, z);
#pragma unroll
    for (int r = 0; r < RPT; ++r) s2[r] = 0.f;
#pragma unroll 4
    for (int t = 0; t < IC; ++t) {
        float4 q = sh[t];
#pragma unroll
        for (int r = 0; r < RPT; ++r) {
            float dx = x[r] - q.x, dy = y[r] - q.y, dz = z[r] - q.z;
            float d2 = fmaf(dz, dz, fmaf(dy, dy, dx * dx));
            float sq = __builtin_amdgcn_sqrtf(fmaxf(d2, 1e-12f));
            s2[r] = fmaf(q.w, sq, s2[r]);
        }
    }
#pragma unroll
    for (int r = 0; r < RPT; ++r)
        P3b[((size_t)bb * n + i0 + r) * C + chunk] = s2[r];
}

__global__ __launch_bounds__(BLOCK)
void emd_final(const float* __restrict__ a, const float* __restrict__ P3b,
               float* __restrict__ cost, int n, int C)
{
    const int bb = blockIdx.z;
    const int i  = blockIdx.x * BLOCK + threadIdx.x;
    size_t ri = (size_t)bb * n + i;
    const float* pb = P3b + ri * C;
    float s2 = 0.f;
    for (int c = 0; c < C; ++c) s2 += pb[c];
    float cv = wave_reduce_add(a[ri] * s2);
    if ((threadIdx.x & 63) == 0) atomicAdd(&cost[bb], cv);
}

extern "C" void kernel_launch(void* const* d_in, const int* in_sizes, int n_in,
                              void* d_out, int out_size, void* d_ws, size_t ws_size,
                              hipStream_t stream)
{
    const float* xyz1 = (const float*)d_in[0];
    const float* xyz2 = (const float*)d_in[1];
    const int b = out_size;                 // 4
    const int n = in_sizes[0] / (3 * b);    // 4096
    const int m = in_sizes[1] / (3 * b);    // 4096
    const int C  = m / IC;                  // row-partial count (j chunks)
    const int C2 = n / IC;                  // col-partial count (i chunks)

    float* ws    = (float*)d_ws;
    float* satlA = ws; ws += (size_t)b * n;
    float* satlB = ws; ws += (size_t)b * n;
    float* satrA = ws; ws += (size_t)b * m;
    float* satrB = ws; ws += (size_t)b * m;
    float* aA    = ws; ws += (size_t)b * n;
    float* aB    = ws; ws += (size_t)b * n;
    float* P1p   = ws; ws += (size_t)b * n * C;
    float* P2p   = ws; ws += (size_t)b * m * C2;
    float* P3a   = ws; ws += (size_t)b * n * C;
    float* P3b   = ws; ws += (size_t)b * n * C;

    float* out = (float*)d_out;

    const int mx = n > m ? n : m;
    const float fl = (float)(mx / n), fr = (float)(mx / m);

    emd_init<<<dim3((b * mx + BLOCK - 1) / BLOCK), BLOCK, 0, stream>>>(
        satlA, satrA, out, fl, fr, b, n, m);

    const double LOG2E = 1.4426950408889634074;
    const double levels[11] = {-65536.0, -16384.0, -4096.0, -1024.0, -256.0,
                               -64.0, -16.0, -4.0, -1.0, -0.25, 0.0};
    float lsv[11];
    for (int k = 0; k < 11; ++k) lsv[k] = (float)(levels[k] * LOG2E);

    const dim3 g1(n / ROWS, m / IC, b);   // outer over xyz1 rows
    const dim3 g2(m / ROWS, n / IC, b);   // outer over xyz2 rows

    emd_pass1<<<g1, BLOCK, 0, stream>>>(xyz1, xyz2, satrA, P1p, lsv[0], n, m, C);
    emd_pass2<<<g2, BLOCK, 0, stream>>>(xyz2, xyz1, satlA, satlB, aA, aA,
                                        P1p, P3a, P3b, P2p, out,
                                        lsv[0], n, m, C, C2, 1);
    for (int L = 0; L < 10; ++L) {
        float* sc_ = (L % 2 == 0) ? satrA : satrB;
        float* sn_ = (L % 2 == 0) ? satrB : satrA;
        emd_fused<<<g1, BLOCK, 0, stream>>>(xyz1, xyz2, sc_, sn_, P2p,
                                            P3a, P3b, P1p,
                                            lsv[L], lsv[L + 1], n, m, C2, C);
        const int Lp = L + 1;
        float* slP = ((Lp + 1) % 2 == 0) ? satlA : satlB;
        float* slN = (Lp % 2 == 0)       ? satlA : satlB;
        float* aP  = ((Lp + 1) % 2 == 0) ? aA : aB;
        float* aO  = (Lp % 2 == 0)       ? aA : aB;
        emd_pass2<<<g2, BLOCK, 0, stream>>>(xyz2, xyz1, slP, slN, aP, aO,
                                            P1p, P3a, P3b, P2p, out,
                                            lsv[Lp], n, m, C, C2, 0);
    }
    emd_pass3_last<<<g1, BLOCK, 0, stream>>>(xyz1, xyz2, satrA, P2p, P3b, n, m, C2, C);
    emd_final<<<dim3(n / BLOCK, 1, b), BLOCK, 0, stream>>>(aA, P3b, out, n, C);
}